// Round 3
// baseline (70.157 us; speedup 1.0000x reference)
//
#include <hip/hip_runtime.h>

// out[b,l,c,d] = p(c)*x0[d] + q(c)*x1[d]  (rank-2 outer product; x has L=2 so
// the 64-wide sliding window sees only taps s0=32-l, s1=33-l).
//   p(c) = x0[c]*F[s0,s0] + x1[c]*F[s1,s0]
//   q(c) = x0[c]*F[s0,s1] + x1[c]*F[s1,s1],  F = filt[0][l]
//
// Layouts (row-major flat):
//   x:    (32, 1024, 2)       -> x[(b*1024 + c)*2 + ch]
//   filt: (1, 2, 64, 64)      -> filt[(l*64 + s)*64 + t]
//   out:  (32, 2, 1024, 1024) -> out[((b*2 + l)*1024 + c)*1024 + d]
//
// Pure store-bound: 268.4 MB writes, ~0.5 MB reads (L2-resident).
// Each thread: 8 contiguous outputs along d = two adjacent 16B NON-TEMPORAL
// stores (nt flag -> no cache allocate; output >> LLC anyway). Native
// ext_vector_type needed: __builtin_nontemporal_store rejects HIP float4.

typedef __attribute__((ext_vector_type(4))) float f32x4;

__global__ __launch_bounds__(256) void filter_rank2_kernel(
    const float* __restrict__ x, const float* __restrict__ filt,
    float* __restrict__ out) {
  const long long idx = (long long)blockIdx.x * 256 + threadIdx.x;
  const int d8 = (int)(idx & 127);           // 8-float chunk index along d
  const int c  = (int)((idx >> 7) & 1023);
  const int l  = (int)((idx >> 17) & 1);
  const int b  = (int)(idx >> 18);

  const int s0 = 32 - l, s1 = 33 - l;
  const float* F = filt + l * 4096;
  const float a00 = F[s0 * 64 + s0];
  const float a01 = F[s0 * 64 + s1];
  const float a10 = F[s1 * 64 + s0];
  const float a11 = F[s1 * 64 + s1];

  const float2* xb = (const float2*)(x + (long long)b * 2048);  // [c]->(x0,x1)
  const float2 xc = xb[c];
  const float p = xc.x * a00 + xc.y * a10;
  const float q = xc.x * a01 + xc.y * a11;

  const int d0 = d8 * 8;
  const f32x4* xd = (const f32x4*)(xb + d0);  // 4 x 16B = 8 (x0,x1) pairs
  const f32x4 t0 = xd[0], t1 = xd[1], t2 = xd[2], t3 = xd[3];

  f32x4 o0, o1;
  o0.x = p * t0.x + q * t0.y;
  o0.y = p * t0.z + q * t0.w;
  o0.z = p * t1.x + q * t1.y;
  o0.w = p * t1.z + q * t1.w;
  o1.x = p * t2.x + q * t2.y;
  o1.y = p * t2.z + q * t2.w;
  o1.z = p * t3.x + q * t3.y;
  o1.w = p * t3.z + q * t3.w;

  f32x4* op = (f32x4*)(out + idx * 8);
  __builtin_nontemporal_store(o0, op);
  __builtin_nontemporal_store(o1, op + 1);
}

extern "C" void kernel_launch(void* const* d_in, const int* in_sizes, int n_in,
                              void* d_out, int out_size, void* d_ws, size_t ws_size,
                              hipStream_t stream) {
  const float* x    = (const float*)d_in[0];
  const float* filt = (const float*)d_in[1];
  float* out        = (float*)d_out;

  // 32*2*1024*1024 outputs / 8 per thread / 256 threads per block
  const int blocks = 32768;
  filter_rank2_kernel<<<blocks, 256, 0, stream>>>(x, filt, out);
}

// Round 4
// 44.451 us; speedup vs baseline: 1.5783x; 1.5783x over previous
//
#include <hip/hip_runtime.h>

// out[b,l,c,d] = p(c)*x0[d] + q(c)*x1[d]  (rank-2 outer product; x has L=2 so
// the 64-wide sliding window sees only taps s0=32-l, s1=33-l).
//   p(c) = x0[c]*F[s0,s0] + x1[c]*F[s1,s0]
//   q(c) = x0[c]*F[s0,s1] + x1[c]*F[s1,s1],  F = filt[0][l]
//
// Layouts (row-major flat):
//   x:    (32, 1024, 2)       -> x[(b*1024 + c)*2 + ch]
//   filt: (1, 2, 64, 64)      -> filt[(l*64 + s)*64 + t]
//   out:  (32, 2, 1024, 1024) -> out[((b*2 + l)*1024 + c)*1024 + d]
//
// Store-bound: 268.4 MB writes. R3 lesson: nt + lane-stride-32B stores =
// partial-line HBM writes (50->70us). Here: REGULAR stores, each store
// instruction is wave-contiguous (4 waves x 1KB = one full 4KB row), and
// each block writes 4 rows (c0..c0+3) reusing the same xd loads:
//   thread t: d = 4t..4t+3; 4 stores, one per row, each a full-row pass.

typedef __attribute__((ext_vector_type(4))) float f32x4;

__global__ __launch_bounds__(256) void filter_rank2_kernel(
    const float* __restrict__ x, const float* __restrict__ filt,
    float* __restrict__ out) {
  const int B   = blockIdx.x;
  const int tid = threadIdx.x;
  const int r4  = B & 255;         // which group of 4 rows within (b,l)
  const int l   = (B >> 8) & 1;
  const int b   = B >> 9;

  const int s0 = 32 - l, s1 = 33 - l;
  const float* F = filt + l * 4096;       // b,l block-uniform -> scalar loads
  const float a00 = F[s0 * 64 + s0];
  const float a01 = F[s0 * 64 + s1];
  const float a10 = F[s1 * 64 + s0];
  const float a11 = F[s1 * 64 + s1];

  const float* xb = x + (long long)b * 2048;   // (x0,x1) pairs along c
  const int c0 = r4 * 4;
  const f32x4 xc01 = *(const f32x4*)(xb + 2 * c0);      // pairs c0, c0+1
  const f32x4 xc23 = *(const f32x4*)(xb + 2 * c0 + 4);  // pairs c0+2, c0+3

  float p[4], q[4];
  p[0] = xc01.x * a00 + xc01.y * a10;  q[0] = xc01.x * a01 + xc01.y * a11;
  p[1] = xc01.z * a00 + xc01.w * a10;  q[1] = xc01.z * a01 + xc01.w * a11;
  p[2] = xc23.x * a00 + xc23.y * a10;  q[2] = xc23.x * a01 + xc23.y * a11;
  p[3] = xc23.z * a00 + xc23.w * a10;  q[3] = xc23.z * a01 + xc23.w * a11;

  const int d0 = tid * 4;                       // 4 d-values per thread
  const f32x4 t0 = *(const f32x4*)(xb + 2 * d0);      // pairs d0, d0+1
  const f32x4 t1 = *(const f32x4*)(xb + 2 * d0 + 4);  // pairs d0+2, d0+3

  float* ob = out + ((long long)(b * 2 + l) * 1024 + c0) * 1024 + d0;
#pragma unroll
  for (int i = 0; i < 4; ++i) {       // 4 rows, static idx -> regs
    f32x4 o;
    o.x = p[i] * t0.x + q[i] * t0.y;
    o.y = p[i] * t0.z + q[i] * t0.w;
    o.z = p[i] * t1.x + q[i] * t1.y;
    o.w = p[i] * t1.z + q[i] * t1.w;
    *(f32x4*)(ob + (long long)i * 1024) = o;   // full 4KB row per store instr
  }
}

extern "C" void kernel_launch(void* const* d_in, const int* in_sizes, int n_in,
                              void* d_out, int out_size, void* d_ws, size_t ws_size,
                              hipStream_t stream) {
  const float* x    = (const float*)d_in[0];
  const float* filt = (const float*)d_in[1];
  float* out        = (float*)d_out;

  // 32 b * 2 l * (1024/4) row-groups = 16384 blocks
  const int blocks = 16384;
  filter_rank2_kernel<<<blocks, 256, 0, stream>>>(x, filt, out);
}